// Round 3
// baseline (1709.471 us; speedup 1.0000x reference)
//
#include <hip/hip_runtime.h>
#include <stdint.h>

#define NH 4
#define HD 64
#define DM 256
#define BB 16
#define PLEN 512
#define GLEN 16384
#define ML 16
#define NCH_MAX 32
#define PT 4  // tiles per proj block

typedef __attribute__((ext_vector_type(8))) short bf16x8;
typedef __attribute__((ext_vector_type(4))) short s16x4;
typedef __attribute__((ext_vector_type(4))) float f32x4;
struct fl4 { float x, y, z, w; };

#define MFMA16(a, b, c) __builtin_amdgcn_mfma_f32_16x16x32_bf16((a), (b), (c), 0, 0, 0)

__device__ __forceinline__ float bf2f(short x) {
  union { unsigned u; float f; } v;
  v.u = ((unsigned)(unsigned short)x) << 16;
  return v.f;
}
__device__ __forceinline__ short f2bf(float x) {
  union { float f; unsigned u; } v;
  v.f = x;
  unsigned u = v.u;
  u += 0x7fffu + ((u >> 16) & 1u);  // RNE
  return (short)(u >> 16);
}

// ---------------- dtype detection: fp32-as-bf16 even shorts are wild ----------------
__global__ void detect_dtype(const short* __restrict__ pattern, int* __restrict__ flag) {
  int t = threadIdx.x;
  int bad = 0;
  for (int i = t; i < 4096; i += 256) {
    float v = bf2f(pattern[2 * i]);
    if (!(fabsf(v) < 1e10f)) bad++;  // catches huge AND NaN
  }
  __shared__ int cnt;
  if (t == 0) cnt = 0;
  __syncthreads();
  if (bad) atomicAdd(&cnt, bad);
  __syncthreads();
  if (t == 0) flag[0] = (cnt > 8) ? 1 : 0;  // 1 = inputs are float32
}

// ---------------- fused: dtype-convert + meanpool col-sums + K/V projection ----------------
// 4 tiles of 64 rows per block, double-buffered 2x32KB LDS, ONE barrier per tile.
// T14 async-STAGE: next tile's fp32 loads issued BEFORE this tile's 128-MFMA compute;
// convert at the compute half-point (frees 32 staging regs -> 16; VALU hides under MFMA).
// Column sums for graph mean-pool: waves 0-3 re-read the (L2/L3-hot) source column-wise,
// atomicAdd into per-(b,m)-segment partials (exact fp32; no LDS scratch).
__global__ __launch_bounds__(512, 4) void proj_kv_fused(
    const void* __restrict__ Xraw, const short* __restrict__ WkT,
    const short* __restrict__ WvT, short* __restrict__ Kout,
    short* __restrict__ Vt, int L, float* __restrict__ partials,
    const int* __restrict__ flag) {
  __shared__ __align__(16) short Xs[2][64 * DM];  // 64 KB
  const int isf = flag[0];
  const int t = threadIdx.x;
  const int tc2 = t & 31, tr2 = t >> 5;  // stage: 8-col chunk, row-within-16
  const int wave = t >> 6, lane = t & 63, quad = lane >> 4, l16 = lane & 15;
  const int kv = wave >> 2;
  const int wc = (wave & 3) * 64;
  const short* WT = kv ? WvT : WkT;  // [n][k] bf16, L2-resident
  const int tile0 = blockIdx.x * PT;

  fl4 Rf[8];    // fp32 prefetch (32 regs, live only until CVTREG)
  bf16x8 Rb[4]; // converted staging (16 regs)

  auto ISSUE = [&](int tile) {
    const float* xf = (const float*)Xraw + (size_t)tile * (64 * DM) + tc2 * 8;
#pragma unroll
    for (int it = 0; it < 4; it++) {
      size_t ro = (size_t)(it * 16 + tr2) * DM;
      Rf[it * 2] = *(const fl4*)(xf + ro);
      Rf[it * 2 + 1] = *(const fl4*)(xf + ro + 4);
    }
  };
  auto CVTREG = [&]() {
#pragma unroll
    for (int it = 0; it < 4; it++) {
      fl4 v0 = Rf[it * 2], v1 = Rf[it * 2 + 1];
      bf16x8 o;
      o[0] = f2bf(v0.x); o[1] = f2bf(v0.y); o[2] = f2bf(v0.z); o[3] = f2bf(v0.w);
      o[4] = f2bf(v1.x); o[5] = f2bf(v1.y); o[6] = f2bf(v1.z); o[7] = f2bf(v1.w);
      Rb[it] = o;
    }
  };
  auto WRITE = [&](int buf) {
    short* xs = &Xs[buf][0];
#pragma unroll
    for (int it = 0; it < 4; it++) {
      int row = it * 16 + tr2;
      *(bf16x8*)(xs + row * DM + (tc2 ^ (row & 7)) * 8) = Rb[it];
    }
  };
  auto STAGE_BF16 = [&](int tile, int buf) {
    const short* xb = (const short*)Xraw + (size_t)tile * (64 * DM) + tc2 * 8;
    short* xs = &Xs[buf][0];
#pragma unroll
    for (int it = 0; it < 4; it++) {
      int row = it * 16 + tr2;
      bf16x8 v = *(const bf16x8*)(xb + (size_t)row * DM);
      *(bf16x8*)(xs + row * DM + (tc2 ^ (row & 7)) * 8) = v;
    }
  };
  auto COLSUM = [&](int tile) {  // waves 0-3 only; exact fp32 column sums
    if (partials == nullptr || t >= DM) return;
    int seg = (tile * 64) >> 10;  // (b*ML + m)
    float s = 0.f;
    if (isf) {
      const float* xf = (const float*)Xraw + (size_t)tile * (64 * DM) + t;
#pragma unroll 8
      for (int r = 0; r < 64; r++) s += xf[(size_t)r * DM];
    } else {
      const short* xb = (const short*)Xraw + (size_t)tile * (64 * DM) + t;
#pragma unroll 8
      for (int r = 0; r < 64; r++) s += bf2f(xb[(size_t)r * DM]);
    }
    atomicAdd(partials + (size_t)seg * DM + t, s);
  };

  if (isf) { ISSUE(tile0); CVTREG(); }
#pragma unroll 2
  for (int tt = 0; tt < PT; tt++) {
    const int tile = tile0 + tt, buf = tt & 1;
    if (isf) WRITE(buf); else STAGE_BF16(tile, buf);
    __syncthreads();  // buf visible; also fences buf reuse from 2 tiles ago
    if (isf && tt + 1 < PT) ISSUE(tile + 1);  // in flight across the MFMAs below
    COLSUM(tile);
    f32x4 z4 = {0.f, 0.f, 0.f, 0.f};
    f32x4 acc[4][4];
#pragma unroll
    for (int i = 0; i < 4; i++)
#pragma unroll
      for (int j = 0; j < 4; j++) acc[i][j] = z4;
    const short* xs = &Xs[buf][0];
#pragma unroll
    for (int kh = 0; kh < 2; kh++) {
#pragma unroll
      for (int k2 = 0; k2 < 4; k2++) {
        const int kk = kh * 4 + k2;
        bf16x8 bw[4];
#pragma unroll
        for (int ct = 0; ct < 4; ct++)
          bw[ct] = *(const bf16x8*)(WT + (size_t)(wc + ct * 16 + l16) * DM + kk * 32 + quad * 8);
#pragma unroll
        for (int rt = 0; rt < 4; rt++) {
          int rw = rt * 16 + l16;
          bf16x8 a = *(const bf16x8*)(xs + rw * DM + (((kk * 4 + quad) ^ (rw & 7)) * 8));
#pragma unroll
          for (int ct = 0; ct < 4; ct++)
            acc[rt][ct] = MFMA16(a, bw[ct], acc[rt][ct]);
        }
      }
      if (kh == 0 && isf && tt + 1 < PT) CVTREG();  // half-point: frees Rf, VALU under MFMA
    }
    const int row0 = tile * 64;
    if (kv == 0) {
#pragma unroll
      for (int rt = 0; rt < 4; rt++)
#pragma unroll
        for (int ct = 0; ct < 4; ct++) {
          int col = wc + ct * 16 + l16;
#pragma unroll
          for (int r = 0; r < 4; r++)
            Kout[(size_t)(row0 + rt * 16 + quad * 4 + r) * DM + col] = f2bf(acc[rt][ct][r]);
        }
    } else {
      int bb = row0 / L, j0v = row0 % L;
#pragma unroll
      for (int rt = 0; rt < 4; rt++) {
        int j = j0v + rt * 16 + quad * 4;
#pragma unroll
        for (int ct = 0; ct < 4; ct++) {
          int c = wc + ct * 16 + l16;
          s16x4 pv;
#pragma unroll
          for (int r = 0; r < 4; r++) pv[r] = f2bf(acc[rt][ct][r]);
          *(s16x4*)(Vt + ((size_t)bb * DM + c) * L + j) = pv;
        }
      }
    }
  }
}

// ---------------- finalize mean + first q-projection ----------------
// partials: one row per (b,m) segment (atomic-accumulated column sums over 1024 rows)
__global__ __launch_bounds__(256) void finalize_q0(
    const float* __restrict__ partials, const void* __restrict__ Wq,
    float* __restrict__ mem, short* __restrict__ hq, const int* __restrict__ flag) {
  int b = blockIdx.x >> 4, m = blockIdx.x & 15;
  int t = threadIdx.x;
  int isf = flag[0];
  float s = partials[((size_t)b * ML + m) * DM + t];
  float v = s * (1.0f / 1024.0f);
  __shared__ float memrow[256];
  memrow[t] = bf2f(f2bf(v));  // bf16-rounded copy (matches MFMA path numerics)
  mem[((size_t)b * ML + m) * DM + t] = v;
  __syncthreads();
  float acc = 0.f;
  if (isf) {
    const float* wf = (const float*)Wq;
    for (int k = 0; k < 256; k++)
      acc += memrow[k] * bf2f(f2bf(wf[(size_t)k * 256 + t]));
  } else {
    const short* wsp = (const short*)Wq;
    for (int k = 0; k < 256; k++)
      acc += memrow[k] * bf2f(wsp[(size_t)k * 256 + t]);
  }
  hq[((size_t)b * ML + m) * DM + t] = f2bf(acc);
}

// ---------------- weight transpose (+dtype convert): W[K][256] -> WT[256][K] bf16 ----------------
struct WTArgs {
  const void* src[10];
  short* dst[10];
  int rows[10];
};

__global__ void transpose_w(WTArgs a, const int* __restrict__ flag) {
  int mid = blockIdx.z;
  int K = a.rows[mid];
  int tk = blockIdx.x, tn = blockIdx.y;
  if (tk * 32 >= K) return;  // block-uniform
  int isf = flag[0];
  __shared__ short tile[32][33];
  const short* src = (const short*)a.src[mid];
  const float* srcf = (const float*)a.src[mid];
  short* dst = a.dst[mid];
  int tx = threadIdx.x, ty = threadIdx.y;  // 32 x 8
  for (int i = 0; i < 32; i += 8) {
    size_t idx = (size_t)(tk * 32 + ty + i) * 256 + tn * 32 + tx;
    tile[ty + i][tx] = isf ? f2bf(srcf[idx]) : src[idx];
  }
  __syncthreads();
  for (int i = 0; i < 32; i += 8)
    dst[(size_t)(tn * 32 + ty + i) * K + tk * 32 + tx] = tile[tx][ty + i];
}

// ---------------- bias convert ----------------
__global__ void conv_bias(const void* p_bg, const void* g_bg, short* out,
                          const int* __restrict__ flag) {
  int t = threadIdx.x;
  int isf = flag[0];
  out[t] = isf ? f2bf(((const float*)p_bg)[t]) : ((const short*)p_bg)[t];
  out[256 + t] = isf ? f2bf(((const float*)g_bg)[t]) : ((const short*)g_bg)[t];
}

// ---------------- flash attention partials (one wave = one head) ----------------
__global__ __launch_bounds__(256, 4) void flash_partial(
    const short* __restrict__ hq, const short* __restrict__ Kb,
    const short* __restrict__ Vt, const int* __restrict__ mask,
    float* __restrict__ pm, float* __restrict__ pl, float* __restrict__ pO,
    int L, int NCH) {
  int ch = blockIdx.x, b = blockIdx.y;
  int C = L / NCH;
  int t = threadIdx.x, wave = t >> 6, lane = t & 63, quad = lane >> 4, l16 = lane & 15;
  __shared__ __align__(16) short Plds[4][512];  // per-wave P tile: [q][32 keys]
  short* myP = &Plds[wave][0];
  const short* qbase = hq + ((size_t)b * ML + l16) * DM + wave * HD;
  bf16x8 aq0 = *(const bf16x8*)(qbase + quad * 8);
  bf16x8 aq1 = *(const bf16x8*)(qbase + 32 + quad * 8);
  f32x4 z = {0.f, 0.f, 0.f, 0.f};
  float m_run[4], l_run[4];
  f32x4 O[4];
#pragma unroll
  for (int r = 0; r < 4; r++) { m_run[r] = -1e30f; l_run[r] = 0.f; }
#pragma unroll
  for (int d = 0; d < 4; d++) O[d] = z;
  int j0 = ch * C;
  const float L2E = 1.44269504f;
  for (int jt = 0; jt < C; jt += 32) {
    f32x4 S[2];
#pragma unroll
    for (int tt = 0; tt < 2; tt++) {
      int j = j0 + jt + tt * 16 + l16;
      const short* kb = Kb + ((size_t)b * L + j) * DM + wave * HD;
      bf16x8 b0 = *(const bf16x8*)(kb + quad * 8);
      bf16x8 b1 = *(const bf16x8*)(kb + 32 + quad * 8);
      f32x4 s = MFMA16(aq0, b0, z);
      s = MFMA16(aq1, b1, s);
      int mk = mask[(size_t)b * L + j];
#pragma unroll
      for (int r = 0; r < 4; r++)
        S[tt][r] = mk ? s[r] * 0.125f : -1e30f;
    }
    float p[2][4], alpha[4];
#pragma unroll
    for (int r = 0; r < 4; r++) {
      float v = fmaxf(S[0][r], S[1][r]);
      v = fmaxf(v, __shfl_xor(v, 1, 16));
      v = fmaxf(v, __shfl_xor(v, 2, 16));
      v = fmaxf(v, __shfl_xor(v, 4, 16));
      v = fmaxf(v, __shfl_xor(v, 8, 16));
      float nm = fmaxf(m_run[r], v);
      alpha[r] = exp2f((m_run[r] - nm) * L2E);
      m_run[r] = nm;
      p[0][r] = exp2f((S[0][r] - nm) * L2E);
      p[1][r] = exp2f((S[1][r] - nm) * L2E);
      float ps = p[0][r] + p[1][r];
      ps += __shfl_xor(ps, 1, 16);
      ps += __shfl_xor(ps, 2, 16);
      ps += __shfl_xor(ps, 4, 16);
      ps += __shfl_xor(ps, 8, 16);
      l_run[r] = l_run[r] * alpha[r] + ps;
    }
#pragma unroll
    for (int d = 0; d < 4; d++)
#pragma unroll
      for (int r = 0; r < 4; r++) O[d][r] *= alpha[r];
#pragma unroll
    for (int tt = 0; tt < 2; tt++)
#pragma unroll
      for (int r = 0; r < 4; r++)
        myP[(quad * 4 + r) * 32 + tt * 16 + l16] = f2bf(p[tt][r]);
    __syncthreads();  // P visible (uniform trip count)
    bf16x8 ap = *(const bf16x8*)(myP + l16 * 32 + quad * 8);
#pragma unroll
    for (int d = 0; d < 4; d++) {
      const short* vb = Vt + ((size_t)b * DM + wave * HD + d * 16 + l16) * L + j0 + jt + quad * 8;
      bf16x8 bv = *(const bf16x8*)vb;
      O[d] = MFMA16(ap, bv, O[d]);
    }
    __syncthreads();  // protect P tile
  }
  size_t base = (((size_t)b * NCH + ch) * NH + wave) * ML;
  if (l16 == 0) {
#pragma unroll
    for (int r = 0; r < 4; r++) {
      pm[base + quad * 4 + r] = m_run[r];
      pl[base + quad * 4 + r] = l_run[r];
    }
  }
#pragma unroll
  for (int d = 0; d < 4; d++)
#pragma unroll
    for (int r = 0; r < 4; r++)
      pO[(base + quad * 4 + r) * 64 + d * 16 + l16] = O[d][r];
}

// ---------------- reduce partials + Wo + gate + (next Wq | final out), per batch ----------------
__global__ __launch_bounds__(256, 2) void epilogue(
    const float* __restrict__ pm, const float* __restrict__ pl,
    const float* __restrict__ pO, int NCH,
    float* __restrict__ mem, const short* __restrict__ WoT,
    const short* __restrict__ WgT, const short* __restrict__ bg,
    const short* __restrict__ WqT, short* __restrict__ hq,
    void* __restrict__ outb, const int* __restrict__ flag) {
  int b = blockIdx.x, t = threadIdx.x;
  int isf = flag[0];
  __shared__ float w_lds[NCH_MAX * 64];
  __shared__ float invL[64];
  __shared__ __align__(16) short vec_bf[ML * DM];
  __shared__ __align__(16) short mem_bf[ML * DM];
  __shared__ __align__(16) short attn_bf[ML * DM];
  __shared__ float attn_f[ML * DM];
  __shared__ __align__(16) short memn_bf[ML * DM];

  for (int idx = t; idx < ML * DM; idx += 256)
    mem_bf[idx] = f2bf(mem[(size_t)b * ML * DM + idx]);
  if (t < 64) {  // t = n*16 + i
    size_t base = (size_t)b * NCH * NH * ML + t;
    float M = -1e30f;
    for (int ch = 0; ch < NCH; ch++)
      M = fmaxf(M, pm[base + (size_t)ch * NH * ML]);
    float Ls = 0.f;
    for (int ch = 0; ch < NCH; ch++) {
      float w = exp2f((pm[base + (size_t)ch * NH * ML] - M) * 1.44269504f);
      w_lds[ch * 64 + t] = w;
      Ls += w * pl[base + (size_t)ch * NH * ML];
    }
    invL[t] = 1.0f / Ls;
  }
  __syncthreads();
  {
    int n = t >> 6, d = t & 63;
    for (int i = 0; i < 16; i++) {
      size_t pb = ((size_t)b * NCH * NH * ML + n * ML + i) * 64 + d;
      float o = 0.f;
      for (int ch = 0; ch < NCH; ch++)
        o += w_lds[ch * 64 + n * 16 + i] * pO[pb + (size_t)ch * NH * ML * 64];
      vec_bf[i * DM + n * 64 + d] = f2bf(o * invL[n * 16 + i]);
    }
  }
  __syncthreads();
  int wave = t >> 6, lane = t & 63, quad = lane >> 4, l16 = lane & 15;
  f32x4 z = {0.f, 0.f, 0.f, 0.f};
  f32x4 acc[4];
#pragma unroll
  for (int c = 0; c < 4; c++) acc[c] = z;
#pragma unroll
  for (int kk = 0; kk < 8; kk++) {
    bf16x8 a = *(const bf16x8*)(vec_bf + l16 * DM + kk * 32 + quad * 8);
#pragma unroll
    for (int ct = 0; ct < 4; ct++) {
      const short* wb = WoT + (size_t)(wave * 64 + ct * 16 + l16) * DM + kk * 32 + quad * 8;
      acc[ct] = MFMA16(a, *(const bf16x8*)wb, acc[ct]);
    }
  }
#pragma unroll
  for (int ct = 0; ct < 4; ct++)
#pragma unroll
    for (int r = 0; r < 4; r++) {
      int row = quad * 4 + r, col = wave * 64 + ct * 16 + l16;
      attn_f[row * DM + col] = acc[ct][r];
      attn_bf[row * DM + col] = f2bf(acc[ct][r]);
    }
  __syncthreads();
  f32x4 g[4];
#pragma unroll
  for (int c = 0; c < 4; c++) g[c] = z;
#pragma unroll
  for (int kk = 0; kk < 16; kk++) {
    bf16x8 a = (kk < 8)
        ? *(const bf16x8*)(mem_bf + l16 * DM + kk * 32 + quad * 8)
        : *(const bf16x8*)(attn_bf + l16 * DM + (kk - 8) * 32 + quad * 8);
#pragma unroll
    for (int ct = 0; ct < 4; ct++) {
      const short* wb = WgT + (size_t)(wave * 64 + ct * 16 + l16) * 512 + kk * 32 + quad * 8;
      g[ct] = MFMA16(a, *(const bf16x8*)wb, g[ct]);
    }
  }
#pragma unroll
  for (int ct = 0; ct < 4; ct++)
#pragma unroll
    for (int r = 0; r < 4; r++) {
      int row = quad * 4 + r, col = wave * 64 + ct * 16 + l16;
      float x = g[ct][r] + bf2f(bg[col]);
      float gg = 1.0f / (1.0f + exp2f(-x * 1.44269504f));
      float old = mem[(size_t)b * ML * DM + row * DM + col];
      float mn = gg * old + (1.0f - gg) * attn_f[row * DM + col];
      mem[(size_t)b * ML * DM + row * DM + col] = mn;
      memn_bf[row * DM + col] = f2bf(mn);
      if (outb) {
        size_t oi = (size_t)b * ML * DM + row * DM + col;
        if (isf) ((float*)outb)[oi] = mn;
        else ((short*)outb)[oi] = f2bf(mn);
      }
    }
  __syncthreads();
  if (WqT) {
    f32x4 h[4];
#pragma unroll
    for (int c = 0; c < 4; c++) h[c] = z;
#pragma unroll
    for (int kk = 0; kk < 8; kk++) {
      bf16x8 a = *(const bf16x8*)(memn_bf + l16 * DM + kk * 32 + quad * 8);
#pragma unroll
      for (int ct = 0; ct < 4; ct++) {
        const short* wb = WqT + (size_t)(wave * 64 + ct * 16 + l16) * DM + kk * 32 + quad * 8;
        h[ct] = MFMA16(a, *(const bf16x8*)wb, h[ct]);
      }
    }
#pragma unroll
    for (int ct = 0; ct < 4; ct++)
#pragma unroll
      for (int r = 0; r < 4; r++)
        hq[(size_t)b * ML * DM + (quad * 4 + r) * DM + wave * 64 + ct * 16 + l16] = f2bf(h[ct][r]);
  }
}

// ---------------- launch ----------------
extern "C" void kernel_launch(void* const* d_in, const int* in_sizes, int n_in,
                              void* d_out, int out_size, void* d_ws, size_t ws_size,
                              hipStream_t stream) {
  const void* pattern = d_in[0];
  const void* graph = d_in[1];
  const int* pmask = (const int*)d_in[2];
  const int* gmask = (const int*)d_in[3];

  char* ws = (char*)d_ws;
  size_t off = 0;
  auto alloc = [&](size_t bytes) {
    void* p = ws + off;
    off = (off + bytes + 255) & ~(size_t)255;
    return p;
  };
  int* flag = (int*)alloc(4);
  // WT order: 0 pWqT 1 pWkT 2 pWvT 3 pWoT 4 pWgT 5 gWqT 6 gWkT 7 gWvT 8 gWoT 9 gWgT
  int rows[10] = {256, 256, 256, 256, 512, 256, 256, 256, 256, 512};
  int srcidx[10] = {4, 5, 6, 7, 8, 10, 11, 12, 13, 14};
  short* WT[10];
  for (int i = 0; i < 10; i++) WT[i] = (short*)alloc((size_t)rows[i] * 256 * 2);
  short* bgc = (short*)alloc(512 * 2);  // [p_bg(256), g_bg(256)]
  short* Kp = (short*)alloc((size_t)BB * PLEN * DM * 2);
  short* Vpt = (short*)alloc((size_t)BB * PLEN * DM * 2);
  short* Kg = (short*)alloc((size_t)BB * GLEN * DM * 2);
  short* Vgt = (short*)alloc((size_t)BB * GLEN * DM * 2);
  short* hq = (short*)alloc((size_t)BB * ML * DM * 2);
  float* memf = (float*)alloc((size_t)BB * ML * DM * 4);
  float* pm = (float*)alloc((size_t)BB * NCH_MAX * NH * ML * 4);
  float* pl = (float*)alloc((size_t)BB * NCH_MAX * NH * ML * 4);
  float* pO = (float*)alloc((size_t)BB * NCH_MAX * NH * ML * 64 * 4);  // 8.4 MB
  float* partG = (float*)alloc((size_t)BB * ML * DM * 4);              // 256 KB
  if (off > ws_size) return;  // ws too small: output stays zero -> diagnostic signal

  detect_dtype<<<dim3(1), dim3(256), 0, stream>>>((const short*)pattern, flag);

  WTArgs wa;
  for (int i = 0; i < 10; i++) {
    wa.src[i] = d_in[srcidx[i]];
    wa.dst[i] = WT[i];
    wa.rows[i] = rows[i];
  }
  transpose_w<<<dim3(16, 8, 10), dim3(32, 8), 0, stream>>>(wa, flag);
  conv_bias<<<dim3(1), dim3(256), 0, stream>>>(d_in[9], d_in[15], bgc, flag);

  // zero the atomic column-sum accumulator, then fused convert+colsum+K/V projection
  hipMemsetAsync(partG, 0, (size_t)BB * ML * DM * 4, stream);
  proj_kv_fused<<<dim3(BB * GLEN / 64 / PT), dim3(512), 0, stream>>>(
      graph, WT[6], WT[7], Kg, Vgt, GLEN, partG, flag);
  proj_kv_fused<<<dim3(BB * PLEN / 64 / PT), dim3(512), 0, stream>>>(
      pattern, WT[1], WT[2], Kp, Vpt, PLEN, (float*)nullptr, flag);
  finalize_q0<<<dim3(BB * ML), dim3(256), 0, stream>>>(partG, d_in[4], memf, hq, flag);

  for (int s = 0; s < 3; s++) {
    // pattern attention
    flash_partial<<<dim3(8, BB), dim3(256), 0, stream>>>(hq, Kp, Vpt, pmask, pm, pl, pO, PLEN, 8);
    epilogue<<<dim3(BB), dim3(256), 0, stream>>>(pm, pl, pO, 8, memf, WT[3], WT[4], bgc,
                                                 (const short*)WT[5], hq, (void*)nullptr, flag);
    // graph attention
    bool last = (s == 2);
    flash_partial<<<dim3(32, BB), dim3(256), 0, stream>>>(hq, Kg, Vgt, gmask, pm, pl, pO, GLEN, 32);
    epilogue<<<dim3(BB), dim3(256), 0, stream>>>(pm, pl, pO, 32, memf, WT[8], WT[9], bgc + 256,
                                                 last ? (const short*)nullptr : (const short*)WT[0],
                                                 hq, last ? d_out : (void*)nullptr, flag);
  }
}

// Round 4
// 1237.101 us; speedup vs baseline: 1.3818x; 1.3818x over previous
//
#include <hip/hip_runtime.h>
#include <stdint.h>

#define NH 4
#define HD 64
#define DM 256
#define BB 16
#define PLEN 512
#define GLEN 16384
#define ML 16
#define NCH_MAX 32
#define TROWS 32            // rows per proj tile
#define TBYTES_F32 32768    // 32*256*4
#define TBYTES_BF16 16384   // 32*256*2

typedef __attribute__((ext_vector_type(8))) short bf16x8;
typedef __attribute__((ext_vector_type(4))) short s16x4;
typedef __attribute__((ext_vector_type(4))) float f32x4;

#define MFMA16(a, b, c) __builtin_amdgcn_mfma_f32_16x16x32_bf16((a), (b), (c), 0, 0, 0)

__device__ __forceinline__ float bf2f(short x) {
  union { unsigned u; float f; } v;
  v.u = ((unsigned)(unsigned short)x) << 16;
  return v.f;
}
__device__ __forceinline__ short f2bf(float x) {
  union { float f; unsigned u; } v;
  v.f = x;
  unsigned u = v.u;
  u += 0x7fffu + ((u >> 16) & 1u);  // RNE
  return (short)(u >> 16);
}
__device__ __forceinline__ bf16x8 pack8(f32x4 a, f32x4 b) {
  bf16x8 o;
  o[0] = f2bf(a[0]); o[1] = f2bf(a[1]); o[2] = f2bf(a[2]); o[3] = f2bf(a[3]);
  o[4] = f2bf(b[0]); o[5] = f2bf(b[1]); o[6] = f2bf(b[2]); o[7] = f2bf(b[3]);
  return o;
}

// ---------------- dtype detection: fp32-as-bf16 even shorts are wild ----------------
__global__ void detect_dtype(const short* __restrict__ pattern, int* __restrict__ flag) {
  int t = threadIdx.x;
  int bad = 0;
  for (int i = t; i < 4096; i += 256) {
    float v = bf2f(pattern[2 * i]);
    if (!(fabsf(v) < 1e10f)) bad++;  // catches huge AND NaN
  }
  __shared__ int cnt;
  if (t == 0) cnt = 0;
  __syncthreads();
  if (bad) atomicAdd(&cnt, bad);
  __syncthreads();
  if (t == 0) flag[0] = (cnt > 8) ? 1 : 0;  // 1 = inputs are float32
}

// ---------------- proj: gload_lds pipelined convert + colsum + K/V projection ----------------
// 32-row tiles. global_load_lds direct HBM->LDS (zero staging VGPRs -> no spill).
// Swizzle applied on the GLOBAL source address (gload_lds dest must be linear):
// 16B granule g of row r stored at g ^ (r&7). Counted vmcnt keeps next tile's
// loads in flight across the barrier (T3/T4-lite); never vmcnt(0) mid-loop.
__device__ __forceinline__ void stage_tile(const void* Xraw, int isf, int tile,
                                           char* lds, int wave, int lane) {
  if (isf) {
    const char* gb = (const char*)Xraw + (size_t)tile * TBYTES_F32;
#pragma unroll
    for (int k = 0; k < 4; k++) {
      int row = k * 8 + wave;  // wave-round covers one 1024B row
      const char* src = gb + row * 1024 + ((lane ^ (row & 7)) * 16);
      char* dst = lds + k * 8192 + wave * 1024;  // +lane*16 implicit (HW)
      __builtin_amdgcn_global_load_lds(
          (const __attribute__((address_space(1))) unsigned int*)src,
          (__attribute__((address_space(3))) unsigned int*)dst, 16, 0, 0);
    }
  } else {
    const char* gb = (const char*)Xraw + (size_t)tile * TBYTES_BF16;
#pragma unroll
    for (int k = 0; k < 2; k++) {
      int row = k * 16 + wave * 2 + (lane >> 5);  // 2 rows per wave-round
      const char* src = gb + row * 512 + (((lane & 31) ^ (row & 7)) * 16);
      char* dst = lds + k * 8192 + wave * 1024;
      __builtin_amdgcn_global_load_lds(
          (const __attribute__((address_space(1))) unsigned int*)src,
          (__attribute__((address_space(3))) unsigned int*)dst, 16, 0, 0);
    }
  }
}

__global__ __launch_bounds__(512, 4) void proj_kv_fused(
    const void* __restrict__ Xraw, const short* __restrict__ WkT,
    const short* __restrict__ WvT, short* __restrict__ Kout,
    short* __restrict__ Vt, int L, float* __restrict__ partials,
    const int* __restrict__ flag, int PTr) {
  __shared__ __align__(16) char Xb[2][TBYTES_F32];  // 64 KB double buffer
  const int isf = flag[0];
  const int t = threadIdx.x;
  const int wave = t >> 6, lane = t & 63, quad = lane >> 4, l16 = lane & 15;
  const int kv = wave >> 2, wc = (wave & 3) * 64;
  const short* WT = kv ? WvT : WkT;  // [n][k] bf16, L2-resident
  const int tile0 = blockIdx.x * PTr;
  const int crow0 = (t >> 8) * 16, ccol = t & 255;  // colsum assignment
  float csum = 0.f;

  stage_tile(Xraw, isf, tile0, &Xb[0][0], wave, lane);  // prologue

  for (int j = 0; j < PTr; j++) {
    const int tile = tile0 + j;
    const int buf = j & 1;
    if (j + 1 < PTr) {
      stage_tile(Xraw, isf, tile + 1, &Xb[buf ^ 1][0], wave, lane);
      if (isf) asm volatile("s_waitcnt vmcnt(4)" ::: "memory");  // tile j landed; j+1 flying
      else     asm volatile("s_waitcnt vmcnt(2)" ::: "memory");
    } else {
      asm volatile("s_waitcnt vmcnt(0)" ::: "memory");
    }
    __builtin_amdgcn_s_barrier();  // buf[j&1] visible to all waves

    // launder WT so the 32 weight loads can't be hoisted out of the tile loop
    int lz = 0;
    asm volatile("" : "+v"(lz));
    const short* WTj = WT + lz;

    const char* xb = &Xb[buf][0];
    f32x4 z4 = {0.f, 0.f, 0.f, 0.f};
    f32x4 acc[2][4];
#pragma unroll
    for (int i = 0; i < 2; i++)
#pragma unroll
      for (int c = 0; c < 4; c++) acc[i][c] = z4;

    if (isf) {
#pragma unroll
      for (int kk = 0; kk < 8; kk++) {
        bf16x8 bw[4];
#pragma unroll
        for (int ct = 0; ct < 4; ct++)
          bw[ct] = *(const bf16x8*)(WTj + (size_t)(wc + ct * 16 + l16) * DM + kk * 32 + quad * 8);
        const int g0 = kk * 8 + quad * 2;
#pragma unroll
        for (int rt = 0; rt < 2; rt++) {
          int rw = rt * 16 + l16, f = rw & 7;
          f32x4 x0 = *(const f32x4*)(xb + rw * 1024 + ((g0 ^ f) * 16));
          f32x4 x1 = *(const f32x4*)(xb + rw * 1024 + (((g0 + 1) ^ f) * 16));
          bf16x8 a = pack8(x0, x1);
#pragma unroll
          for (int ct = 0; ct < 4; ct++) acc[rt][ct] = MFMA16(a, bw[ct], acc[rt][ct]);
        }
      }
    } else {
#pragma unroll
      for (int kk = 0; kk < 8; kk++) {
        bf16x8 bw[4];
#pragma unroll
        for (int ct = 0; ct < 4; ct++)
          bw[ct] = *(const bf16x8*)(WTj + (size_t)(wc + ct * 16 + l16) * DM + kk * 32 + quad * 8);
        const int g = kk * 4 + quad;
#pragma unroll
        for (int rt = 0; rt < 2; rt++) {
          int rw = rt * 16 + l16;
          bf16x8 a = *(const bf16x8*)(xb + rw * 512 + ((g ^ (rw & 7)) * 16));
#pragma unroll
          for (int ct = 0; ct < 4; ct++) acc[rt][ct] = MFMA16(a, bw[ct], acc[rt][ct]);
        }
      }
    }

    if (partials) {  // column partial sums from the LDS-resident tile (exact fp32)
      if (isf) {
#pragma unroll
        for (int i = 0; i < 16; i++) {
          int r = crow0 + i;
          csum += *(const float*)(xb + r * 1024 + (((ccol >> 2) ^ (r & 7)) * 16) + (ccol & 3) * 4);
        }
      } else {
#pragma unroll
        for (int i = 0; i < 16; i++) {
          int r = crow0 + i;
          csum += bf2f(*(const short*)(xb + r * 512 + (((ccol >> 3) ^ (r & 7)) * 16) + (ccol & 7) * 2));
        }
      }
    }

    const int row0 = tile * TROWS;
    if (kv == 0) {
#pragma unroll
      for (int rt = 0; rt < 2; rt++)
#pragma unroll
        for (int ct = 0; ct < 4; ct++) {
          int col = wc + ct * 16 + l16;
#pragma unroll
          for (int r = 0; r < 4; r++)
            Kout[(size_t)(row0 + rt * 16 + quad * 4 + r) * DM + col] = f2bf(acc[rt][ct][r]);
        }
    } else {
      int bb = row0 / L, j0v = row0 % L;
#pragma unroll
      for (int rt = 0; rt < 2; rt++) {
        int jj = j0v + rt * 16 + quad * 4;
#pragma unroll
        for (int ct = 0; ct < 4; ct++) {
          int c = wc + ct * 16 + l16;
          s16x4 pv;
#pragma unroll
          for (int r = 0; r < 4; r++) pv[r] = f2bf(acc[rt][ct][r]);
          *(s16x4*)(Vt + ((size_t)bb * DM + c) * L + jj) = pv;
        }
      }
    }

    asm volatile("" ::: "memory");       // keep LDS reads above the barrier
    __builtin_amdgcn_s_barrier();        // all reads of buf[j&1] done -> reusable
  }

  if (partials) {  // reduce the two 16-row halves, one plain write per block
    float* scrf = (float*)&Xb[0][0];
    if (t >= 256) scrf[t - 256] = csum;
    __syncthreads();
    if (t < 256) partials[(size_t)blockIdx.x * 256 + t] = csum + scrf[t];
  }
}

// ---------------- finalize mean + first q-projection ----------------
// partials: two half-segment rows (512 rows each) per (b,m) segment
__global__ __launch_bounds__(256) void finalize_q0(
    const float* __restrict__ partials, const void* __restrict__ Wq,
    float* __restrict__ mem, short* __restrict__ hq, const int* __restrict__ flag) {
  int b = blockIdx.x >> 4, m = blockIdx.x & 15;
  int seg = b * ML + m;
  int t = threadIdx.x;
  int isf = flag[0];
  float s = partials[(size_t)(2 * seg) * 256 + t] + partials[(size_t)(2 * seg + 1) * 256 + t];
  float v = s * (1.0f / 1024.0f);
  __shared__ float memrow[256];
  memrow[t] = bf2f(f2bf(v));  // bf16-rounded copy (matches MFMA path numerics)
  mem[((size_t)b * ML + m) * DM + t] = v;
  __syncthreads();
  float acc = 0.f;
  if (isf) {
    const float* wf = (const float*)Wq;
    for (int k = 0; k < 256; k++)
      acc += memrow[k] * bf2f(f2bf(wf[(size_t)k * 256 + t]));
  } else {
    const short* wsp = (const short*)Wq;
    for (int k = 0; k < 256; k++)
      acc += memrow[k] * bf2f(wsp[(size_t)k * 256 + t]);
  }
  hq[((size_t)b * ML + m) * DM + t] = f2bf(acc);
}

// ---------------- weight transpose (+dtype convert): W[K][256] -> WT[256][K] bf16 ----------------
struct WTArgs {
  const void* src[10];
  short* dst[10];
  int rows[10];
};

__global__ void transpose_w(WTArgs a, const int* __restrict__ flag) {
  int mid = blockIdx.z;
  int K = a.rows[mid];
  int tk = blockIdx.x, tn = blockIdx.y;
  if (tk * 32 >= K) return;  // block-uniform
  int isf = flag[0];
  __shared__ short tile[32][33];
  const short* src = (const short*)a.src[mid];
  const float* srcf = (const float*)a.src[mid];
  short* dst = a.dst[mid];
  int tx = threadIdx.x, ty = threadIdx.y;  // 32 x 8
  for (int i = 0; i < 32; i += 8) {
    size_t idx = (size_t)(tk * 32 + ty + i) * 256 + tn * 32 + tx;
    tile[ty + i][tx] = isf ? f2bf(srcf[idx]) : src[idx];
  }
  __syncthreads();
  for (int i = 0; i < 32; i += 8)
    dst[(size_t)(tn * 32 + ty + i) * K + tk * 32 + tx] = tile[tx][ty + i];
}

// ---------------- bias convert ----------------
__global__ void conv_bias(const void* p_bg, const void* g_bg, short* out,
                          const int* __restrict__ flag) {
  int t = threadIdx.x;
  int isf = flag[0];
  out[t] = isf ? f2bf(((const float*)p_bg)[t]) : ((const short*)p_bg)[t];
  out[256 + t] = isf ? f2bf(((const float*)g_bg)[t]) : ((const short*)g_bg)[t];
}

// ---------------- flash attention partials (one wave = one head) ----------------
__global__ __launch_bounds__(256, 4) void flash_partial(
    const short* __restrict__ hq, const short* __restrict__ Kb,
    const short* __restrict__ Vt, const int* __restrict__ mask,
    float* __restrict__ pm, float* __restrict__ pl, float* __restrict__ pO,
    int L, int NCH) {
  int ch = blockIdx.x, b = blockIdx.y;
  int C = L / NCH;
  int t = threadIdx.x, wave = t >> 6, lane = t & 63, quad = lane >> 4, l16 = lane & 15;
  __shared__ __align__(16) short Plds[4][512];  // per-wave P tile: [q][32 keys]
  short* myP = &Plds[wave][0];
  const short* qbase = hq + ((size_t)b * ML + l16) * DM + wave * HD;
  bf16x8 aq0 = *(const bf16x8*)(qbase + quad * 8);
  bf16x8 aq1 = *(const bf16x8*)(qbase + 32 + quad * 8);
  f32x4 z = {0.f, 0.f, 0.f, 0.f};
  float m_run[4], l_run[4];
  f32x4 O[4];
#pragma unroll
  for (int r = 0; r < 4; r++) { m_run[r] = -1e30f; l_run[r] = 0.f; }
#pragma unroll
  for (int d = 0; d < 4; d++) O[d] = z;
  int j0 = ch * C;
  const float L2E = 1.44269504f;
  for (int jt = 0; jt < C; jt += 32) {
    f32x4 S[2];
#pragma unroll
    for (int tt = 0; tt < 2; tt++) {
      int j = j0 + jt + tt * 16 + l16;
      const short* kb = Kb + ((size_t)b * L + j) * DM + wave * HD;
      bf16x8 b0 = *(const bf16x8*)(kb + quad * 8);
      bf16x8 b1 = *(const bf16x8*)(kb + 32 + quad * 8);
      f32x4 s = MFMA16(aq0, b0, z);
      s = MFMA16(aq1, b1, s);
      int mk = mask[(size_t)b * L + j];
#pragma unroll
      for (int r = 0; r < 4; r++)
        S[tt][r] = mk ? s[r] * 0.125f : -1e30f;
    }
    float p[2][4], alpha[4];
#pragma unroll
    for (int r = 0; r < 4; r++) {
      float v = fmaxf(S[0][r], S[1][r]);
      v = fmaxf(v, __shfl_xor(v, 1, 16));
      v = fmaxf(v, __shfl_xor(v, 2, 16));
      v = fmaxf(v, __shfl_xor(v, 4, 16));
      v = fmaxf(v, __shfl_xor(v, 8, 16));
      float nm = fmaxf(m_run[r], v);
      alpha[r] = exp2f((m_run[r] - nm) * L2E);
      m_run[r] = nm;
      p[0][r] = exp2f((S[0][r] - nm) * L2E);
      p[1][r] = exp2f((S[1][r] - nm) * L2E);
      float ps = p[0][r] + p[1][r];
      ps += __shfl_xor(ps, 1, 16);
      ps += __shfl_xor(ps, 2, 16);
      ps += __shfl_xor(ps, 4, 16);
      ps += __shfl_xor(ps, 8, 16);
      l_run[r] = l_run[r] * alpha[r] + ps;
    }
#pragma unroll
    for (int d = 0; d < 4; d++)
#pragma unroll
      for (int r = 0; r < 4; r++) O[d][r] *= alpha[r];
#pragma unroll
    for (int tt = 0; tt < 2; tt++)
#pragma unroll
      for (int r = 0; r < 4; r++)
        myP[(quad * 4 + r) * 32 + tt * 16 + l16] = f2bf(p[tt][r]);
    __syncthreads();  // P visible (uniform trip count)
    bf16x8 ap = *(const bf16x8*)(myP + l16 * 32 + quad * 8);
#pragma unroll
    for (int d = 0; d < 4; d++) {
      const short* vb = Vt + ((size_t)b * DM + wave * HD + d * 16 + l16) * L + j0 + jt + quad * 8;
      bf16x8 bv = *(const bf16x8*)vb;
      O[d] = MFMA16(ap, bv, O[d]);
    }
    __syncthreads();  // protect P tile
  }
  size_t base = (((size_t)b * NCH + ch) * NH + wave) * ML;
  if (l16 == 0) {
#pragma unroll
    for (int r = 0; r < 4; r++) {
      pm[base + quad * 4 + r] = m_run[r];
      pl[base + quad * 4 + r] = l_run[r];
    }
  }
#pragma unroll
  for (int d = 0; d < 4; d++)
#pragma unroll
    for (int r = 0; r < 4; r++)
      pO[(base + quad * 4 + r) * 64 + d * 16 + l16] = O[d][r];
}

// ---------------- reduce partials + Wo + gate + (next Wq | final out), per batch ----------------
__global__ __launch_bounds__(256, 2) void epilogue(
    const float* __restrict__ pm, const float* __restrict__ pl,
    const float* __restrict__ pO, int NCH,
    float* __restrict__ mem, const short* __restrict__ WoT,
    const short* __restrict__ WgT, const short* __restrict__ bg,
    const short* __restrict__ WqT, short* __restrict__ hq,
    void* __restrict__ outb, const int* __restrict__ flag) {
  int b = blockIdx.x, t = threadIdx.x;
  int isf = flag[0];
  __shared__ float w_lds[NCH_MAX * 64];
  __shared__ float invL[64];
  __shared__ __align__(16) short vec_bf[ML * DM];
  __shared__ __align__(16) short mem_bf[ML * DM];
  __shared__ __align__(16) short attn_bf[ML * DM];
  __shared__ float attn_f[ML * DM];
  __shared__ __align__(16) short memn_bf[ML * DM];

  for (int idx = t; idx < ML * DM; idx += 256)
    mem_bf[idx] = f2bf(mem[(size_t)b * ML * DM + idx]);
  if (t < 64) {  // t = n*16 + i
    size_t base = (size_t)b * NCH * NH * ML + t;
    float M = -1e30f;
    for (int ch = 0; ch < NCH; ch++)
      M = fmaxf(M, pm[base + (size_t)ch * NH * ML]);
    float Ls = 0.f;
    for (int ch = 0; ch < NCH; ch++) {
      float w = exp2f((pm[base + (size_t)ch * NH * ML] - M) * 1.44269504f);
      w_lds[ch * 64 + t] = w;
      Ls += w * pl[base + (size_t)ch * NH * ML];
    }
    invL[t] = 1.0f / Ls;
  }
  __syncthreads();
  {
    int n = t >> 6, d = t & 63;
    for (int i = 0; i < 16; i++) {
      size_t pb = ((size_t)b * NCH * NH * ML + n * ML + i) * 64 + d;
      float o = 0.f;
      for (int ch = 0; ch < NCH; ch++)
        o += w_lds[ch * 64 + n * 16 + i] * pO[pb + (size_t)ch * NH * ML * 64];
      vec_bf[i * DM + n * 64 + d] = f2bf(o * invL[n * 16 + i]);
    }
  }
  __syncthreads();
  int wave = t >> 6, lane = t & 63, quad = lane >> 4, l16 = lane & 15;
  f32x4 z = {0.f, 0.f, 0.f, 0.f};
  f32x4 acc[4];
#pragma unroll
  for (int c = 0; c < 4; c++) acc[c] = z;
#pragma unroll
  for (int kk = 0; kk < 8; kk++) {
    bf16x8 a = *(const bf16x8*)(vec_bf + l16 * DM + kk * 32 + quad * 8);
#pragma unroll
    for (int ct = 0; ct < 4; ct++) {
      const short* wb = WoT + (size_t)(wave * 64 + ct * 16 + l16) * DM + kk * 32 + quad * 8;
      acc[ct] = MFMA16(a, *(const bf16x8*)wb, acc[ct]);
    }
  }
#pragma unroll
  for (int ct = 0; ct < 4; ct++)
#pragma unroll
    for (int r = 0; r < 4; r++) {
      int row = quad * 4 + r, col = wave * 64 + ct * 16 + l16;
      attn_f[row * DM + col] = acc[ct][r];
      attn_bf[row * DM + col] = f2bf(acc[ct][r]);
    }
  __syncthreads();
  f32x4 g[4];
#pragma unroll
  for (int c = 0; c < 4; c++) g[c] = z;
#pragma unroll
  for (int kk = 0; kk < 16; kk++) {
    bf16x8 a = (kk < 8)
        ? *(const bf16x8*)(mem_bf + l16 * DM + kk * 32 + quad * 8)
        : *(const bf16x8*)(attn_bf + l16 * DM + (kk - 8) * 32 + quad * 8);
#pragma unroll
    for (int ct = 0; ct < 4; ct++) {
      const short* wb = WgT + (size_t)(wave * 64 + ct * 16 + l16) * 512 + kk * 32 + quad * 8;
      g[ct] = MFMA16(a, *(const bf16x8*)wb, g[ct]);
    }
  }
#pragma unroll
  for (int ct = 0; ct < 4; ct++)
#pragma unroll
    for (int r = 0; r < 4; r++) {
      int row = quad * 4 + r, col = wave * 64 + ct * 16 + l16;
      float x = g[ct][r] + bf2f(bg[col]);
      float gg = 1.0f / (1.0f + exp2f(-x * 1.44269504f));
      float old = mem[(size_t)b * ML * DM + row * DM + col];
      float mn = gg * old + (1.0f - gg) * attn_f[row * DM + col];
      mem[(size_t)b * ML * DM + row * DM + col] = mn;
      memn_bf[row * DM + col] = f2bf(mn);
      if (outb) {
        size_t oi = (size_t)b * ML * DM + row * DM + col;
        if (isf) ((float*)outb)[oi] = mn;
        else ((short*)outb)[oi] = f2bf(mn);
      }
    }
  __syncthreads();
  if (WqT) {
    f32x4 h[4];
#pragma unroll
    for (int c = 0; c < 4; c++) h[c] = z;
#pragma unroll
    for (int kk = 0; kk < 8; kk++) {
      bf16x8 a = *(const bf16x8*)(memn_bf + l16 * DM + kk * 32 + quad * 8);
#pragma unroll
      for (int ct = 0; ct < 4; ct++) {
        const short* wb = WqT + (size_t)(wave * 64 + ct * 16 + l16) * DM + kk * 32 + quad * 8;
        h[ct] = MFMA16(a, *(const bf16x8*)wb, h[ct]);
      }
    }
#pragma unroll
    for (int ct = 0; ct < 4; ct++)
#pragma unroll
      for (int r = 0; r < 4; r++)
        hq[(size_t)b * ML * DM + (quad * 4 + r) * DM + wave * 64 + ct * 16 + l16] = f2bf(h[ct][r]);
  }
}

// ---------------- launch ----------------
extern "C" void kernel_launch(void* const* d_in, const int* in_sizes, int n_in,
                              void* d_out, int out_size, void* d_ws, size_t ws_size,
                              hipStream_t stream) {
  const void* pattern = d_in[0];
  const void* graph = d_in[1];
  const int* pmask = (const int*)d_in[2];
  const int* gmask = (const int*)d_in[3];

  char* ws = (char*)d_ws;
  size_t off = 0;
  auto alloc = [&](size_t bytes) {
    void* p = ws + off;
    off = (off + bytes + 255) & ~(size_t)255;
    return p;
  };
  int* flag = (int*)alloc(4);
  // WT order: 0 pWqT 1 pWkT 2 pWvT 3 pWoT 4 pWgT 5 gWqT 6 gWkT 7 gWvT 8 gWoT 9 gWgT
  int rows[10] = {256, 256, 256, 256, 512, 256, 256, 256, 256, 512};
  int srcidx[10] = {4, 5, 6, 7, 8, 10, 11, 12, 13, 14};
  short* WT[10];
  for (int i = 0; i < 10; i++) WT[i] = (short*)alloc((size_t)rows[i] * 256 * 2);
  short* bgc = (short*)alloc(512 * 2);  // [p_bg(256), g_bg(256)]
  short* Kp = (short*)alloc((size_t)BB * PLEN * DM * 2);
  short* Vpt = (short*)alloc((size_t)BB * PLEN * DM * 2);
  short* Kg = (short*)alloc((size_t)BB * GLEN * DM * 2);
  short* Vgt = (short*)alloc((size_t)BB * GLEN * DM * 2);
  short* hq = (short*)alloc((size_t)BB * ML * DM * 2);
  float* memf = (float*)alloc((size_t)BB * ML * DM * 4);
  float* pm = (float*)alloc((size_t)BB * NCH_MAX * NH * ML * 4);
  float* pl = (float*)alloc((size_t)BB * NCH_MAX * NH * ML * 4);
  float* pO = (float*)alloc((size_t)BB * NCH_MAX * NH * ML * 64 * 4);  // 8.4 MB
  float* partG = (float*)alloc((size_t)512 * 256 * 4);                 // 512 KB
  if (off > ws_size) return;  // ws too small: output stays zero -> diagnostic signal

  detect_dtype<<<dim3(1), dim3(256), 0, stream>>>((const short*)pattern, flag);

  WTArgs wa;
  for (int i = 0; i < 10; i++) {
    wa.src[i] = d_in[srcidx[i]];
    wa.dst[i] = WT[i];
    wa.rows[i] = rows[i];
  }
  transpose_w<<<dim3(16, 8, 10), dim3(32, 8), 0, stream>>>(wa, flag);
  conv_bias<<<dim3(1), dim3(256), 0, stream>>>(d_in[9], d_in[15], bgc, flag);

  // pipelined convert + colsum + K/V projection
  // graph: 512 blocks x 16 tiles (half-segment each); pattern: 256 blocks x 1 tile
  proj_kv_fused<<<dim3(512), dim3(512), 0, stream>>>(
      graph, WT[6], WT[7], Kg, Vgt, GLEN, partG, flag, 16);
  proj_kv_fused<<<dim3(256), dim3(512), 0, stream>>>(
      pattern, WT[1], WT[2], Kp, Vpt, PLEN, (float*)nullptr, flag, 1);
  finalize_q0<<<dim3(BB * ML), dim3(256), 0, stream>>>(partG, d_in[4], memf, hq, flag);

  for (int s = 0; s < 3; s++) {
    // pattern attention
    flash_partial<<<dim3(8, BB), dim3(256), 0, stream>>>(hq, Kp, Vpt, pmask, pm, pl, pO, PLEN, 8);
    epilogue<<<dim3(BB), dim3(256), 0, stream>>>(pm, pl, pO, 8, memf, WT[3], WT[4], bgc,
                                                 (const short*)WT[5], hq, (void*)nullptr, flag);
    // graph attention
    bool last = (s == 2);
    flash_partial<<<dim3(32, BB), dim3(256), 0, stream>>>(hq, Kg, Vgt, gmask, pm, pl, pO, GLEN, 32);
    epilogue<<<dim3(BB), dim3(256), 0, stream>>>(pm, pl, pO, 32, memf, WT[8], WT[9], bgc + 256,
                                                 last ? (const short*)nullptr : (const short*)WT[0],
                                                 hq, last ? d_out : (void*)nullptr, flag);
  }
}

// Round 6
// 1088.087 us; speedup vs baseline: 1.5711x; 1.1369x over previous
//
#include <hip/hip_runtime.h>
#include <stdint.h>

#define NH 4
#define HD 64
#define DM 256
#define BB 16
#define PLEN 512
#define GLEN 16384
#define ML 16
#define NCH_MAX 32

typedef __attribute__((ext_vector_type(8))) short bf16x8;
typedef __attribute__((ext_vector_type(4))) short s16x4;
typedef __attribute__((ext_vector_type(4))) float f32x4;
struct fl4 { float x, y, z, w; };

#define MFMA16(a, b, c) __builtin_amdgcn_mfma_f32_16x16x32_bf16((a), (b), (c), 0, 0, 0)

__device__ __forceinline__ float bf2f(short x) {
  union { unsigned u; float f; } v;
  v.u = ((unsigned)(unsigned short)x) << 16;
  return v.f;
}
__device__ __forceinline__ short f2bf(float x) {
  union { float f; unsigned u; } v;
  v.f = x;
  unsigned u = v.u;
  u += 0x7fffu + ((u >> 16) & 1u);  // RNE
  return (short)(u >> 16);
}

// ---------------- dtype detection: fp32-as-bf16 even shorts are wild ----------------
__global__ void detect_dtype(const short* __restrict__ pattern, int* __restrict__ flag) {
  int t = threadIdx.x;
  int bad = 0;
  for (int i = t; i < 4096; i += 256) {
    float v = bf2f(pattern[2 * i]);
    if (!(fabsf(v) < 1e10f)) bad++;  // catches huge AND NaN
  }
  __shared__ int cnt;
  if (t == 0) cnt = 0;
  __syncthreads();
  if (bad) atomicAdd(&cnt, bad);
  __syncthreads();
  if (t == 0) flag[0] = (cnt > 8) ? 1 : 0;  // 1 = inputs are float32
}

// ---------------- fused: dtype-convert + meanpool partial sums + K/V projection ----------------
// (round-1 structure, measured 238 us on graph: 64-row block, one barrier, reg staging)
__global__ __launch_bounds__(512, 4) void proj_kv_fused(
    const void* __restrict__ Xraw, const short* __restrict__ WkT,
    const short* __restrict__ WvT, short* __restrict__ Kout,
    short* __restrict__ Vt, int L, float* __restrict__ partials,
    const int* __restrict__ flag) {
  __shared__ __align__(16) short Xs[64 * DM];  // 32 KB, swizzled
  __shared__ float scr[16 * DM];               // 16 KB, col-sum scratch
  const int isf = flag[0];
  const int t = threadIdx.x;
  const int row0 = blockIdx.x * 64;
  const int tc2 = t & 31, tr2 = t >> 5;  // col-chunk (8 elems), row-within-16
  float s[8];
#pragma unroll
  for (int j = 0; j < 8; j++) s[j] = 0.f;
  if (isf) {
    const float* xf = (const float*)Xraw + (size_t)row0 * DM + tc2 * 8;
#pragma unroll
    for (int it = 0; it < 4; it++) {
      int row = it * 16 + tr2;
      fl4 v0 = *(const fl4*)(xf + (size_t)row * DM);
      fl4 v1 = *(const fl4*)(xf + (size_t)row * DM + 4);
      s[0] += v0.x; s[1] += v0.y; s[2] += v0.z; s[3] += v0.w;
      s[4] += v1.x; s[5] += v1.y; s[6] += v1.z; s[7] += v1.w;
      bf16x8 o;
      o[0] = f2bf(v0.x); o[1] = f2bf(v0.y); o[2] = f2bf(v0.z); o[3] = f2bf(v0.w);
      o[4] = f2bf(v1.x); o[5] = f2bf(v1.y); o[6] = f2bf(v1.z); o[7] = f2bf(v1.w);
      *(bf16x8*)(Xs + row * DM + (tc2 ^ (row & 7)) * 8) = o;
    }
  } else {
    const short* xb = (const short*)Xraw + (size_t)row0 * DM + tc2 * 8;
#pragma unroll
    for (int it = 0; it < 4; it++) {
      int row = it * 16 + tr2;
      bf16x8 v = *(const bf16x8*)(xb + (size_t)row * DM);
#pragma unroll
      for (int j = 0; j < 8; j++) s[j] += bf2f(v[j]);
      *(bf16x8*)(Xs + row * DM + (tc2 ^ (row & 7)) * 8) = v;
    }
  }
  if (partials) {
#pragma unroll
    for (int j = 0; j < 8; j++) scr[tr2 * DM + tc2 * 8 + j] = s[j];
  }
  __syncthreads();  // Xs (and scr) visible — the only barrier
  if (partials && t < DM) {
    float a = 0.f;
#pragma unroll
    for (int i = 0; i < 16; i++) a += scr[i * DM + t];
    partials[(size_t)blockIdx.x * DM + t] = a;
  }
  const int wave = t >> 6, lane = t & 63, quad = lane >> 4, l16 = lane & 15;
  const int kv = wave >> 2;
  const int wc = (wave & 3) * 64;
  const short* WT = kv ? WvT : WkT;  // [n][k] bf16, L2-resident (128 KB each)
  f32x4 z = {0.f, 0.f, 0.f, 0.f};
  f32x4 acc[4][4];
#pragma unroll
  for (int i = 0; i < 4; i++)
#pragma unroll
    for (int j = 0; j < 4; j++) acc[i][j] = z;
#pragma unroll
  for (int kk = 0; kk < 8; kk++) {
    bf16x8 a[4], bw[4];
#pragma unroll
    for (int rt = 0; rt < 4; rt++) {
      int rw = rt * 16 + l16;
      a[rt] = *(const bf16x8*)(Xs + rw * DM + (((kk * 4 + quad) ^ (rw & 7)) * 8));
    }
#pragma unroll
    for (int ct = 0; ct < 4; ct++)
      bw[ct] = *(const bf16x8*)(WT + (size_t)(wc + ct * 16 + l16) * DM + kk * 32 + quad * 8);
#pragma unroll
    for (int rt = 0; rt < 4; rt++)
#pragma unroll
      for (int ct = 0; ct < 4; ct++)
        acc[rt][ct] = MFMA16(a[rt], bw[ct], acc[rt][ct]);
  }
  if (kv == 0) {
#pragma unroll
    for (int rt = 0; rt < 4; rt++)
#pragma unroll
      for (int ct = 0; ct < 4; ct++) {
        int col = wc + ct * 16 + l16;
#pragma unroll
        for (int r = 0; r < 4; r++)
          Kout[(size_t)(row0 + rt * 16 + quad * 4 + r) * DM + col] = f2bf(acc[rt][ct][r]);
      }
  } else {
    int bb = row0 / L, j0v = row0 % L;
#pragma unroll
    for (int rt = 0; rt < 4; rt++) {
      int j = j0v + rt * 16 + quad * 4;
#pragma unroll
      for (int ct = 0; ct < 4; ct++) {
        int c = wc + ct * 16 + l16;
        s16x4 pv;
#pragma unroll
        for (int r = 0; r < 4; r++) pv[r] = f2bf(acc[rt][ct][r]);
        *(s16x4*)(Vt + ((size_t)bb * DM + c) * L + j) = pv;
      }
    }
  }
}

// ---------------- finalize mean + first q-projection ----------------
// partials are per-64-row blocks: 16 per (b,m) segment of 1024 rows.
__global__ __launch_bounds__(256) void finalize_q0(
    const float* __restrict__ partials, const void* __restrict__ Wq,
    float* __restrict__ mem, short* __restrict__ hq, const int* __restrict__ flag) {
  int b = blockIdx.x >> 4, m = blockIdx.x & 15;
  int t = threadIdx.x;
  int isf = flag[0];
  int p0 = b * 256 + m * 16;  // first partial-block of this (b,m) segment
  float s = 0.f;
#pragma unroll
  for (int i = 0; i < 16; i++) s += partials[(size_t)(p0 + i) * 256 + t];
  float v = s * (1.0f / 1024.0f);
  __shared__ float memrow[256];
  memrow[t] = bf2f(f2bf(v));  // bf16-rounded copy (matches MFMA path numerics)
  mem[((size_t)b * ML + m) * DM + t] = v;
  __syncthreads();
  float acc = 0.f;
  if (isf) {
    const float* wf = (const float*)Wq;
    for (int k = 0; k < 256; k++)
      acc += memrow[k] * bf2f(f2bf(wf[(size_t)k * 256 + t]));
  } else {
    const short* wsp = (const short*)Wq;
    for (int k = 0; k < 256; k++)
      acc += memrow[k] * bf2f(wsp[(size_t)k * 256 + t]);
  }
  hq[((size_t)b * ML + m) * DM + t] = f2bf(acc);
}

// ---------------- weight transpose (+dtype convert): W[K][256] -> WT[256][K] bf16 ----------------
struct WTArgs {
  const void* src[10];
  short* dst[10];
  int rows[10];
};

__global__ void transpose_w(WTArgs a, const int* __restrict__ flag) {
  int mid = blockIdx.z;
  int K = a.rows[mid];
  int tk = blockIdx.x, tn = blockIdx.y;
  if (tk * 32 >= K) return;  // block-uniform
  int isf = flag[0];
  __shared__ short tile[32][33];
  const short* src = (const short*)a.src[mid];
  const float* srcf = (const float*)a.src[mid];
  short* dst = a.dst[mid];
  int tx = threadIdx.x, ty = threadIdx.y;  // 32 x 8
  for (int i = 0; i < 32; i += 8) {
    size_t idx = (size_t)(tk * 32 + ty + i) * 256 + tn * 32 + tx;
    tile[ty + i][tx] = isf ? f2bf(srcf[idx]) : src[idx];
  }
  __syncthreads();
  for (int i = 0; i < 32; i += 8)
    dst[(size_t)(tn * 32 + ty + i) * K + tk * 32 + tx] = tile[tx][ty + i];
}

// ---------------- bias convert ----------------
__global__ void conv_bias(const void* p_bg, const void* g_bg, short* out,
                          const int* __restrict__ flag) {
  int t = threadIdx.x;
  int isf = flag[0];
  out[t] = isf ? f2bf(((const float*)p_bg)[t]) : ((const short*)p_bg)[t];
  out[256 + t] = isf ? f2bf(((const float*)g_bg)[t]) : ((const short*)g_bg)[t];
}

// ---------------- flash attention partials (one wave = one head) ----------------
// ONLY change vs the 1108.8us config: swapped QK^T — compute mfma(K, Q) so each
// lane holds scores for ONE query (q = l16). Key-reduction becomes 7 in-lane
// ops + 2 shfl_xor (was 32 shfl); zero workgroup barriers (P tile is wave-private).
// Wave-local DS write->read ordered by builtin s_waitcnt(lgkmcnt 0) + sched_barrier(0)
// (rule #18: asm-"memory" alone does NOT stop MFMA hoisting past the wait).
// Grid, NCH, pm/pl/pO layouts identical to the round-1 version.
__global__ __launch_bounds__(256, 4) void flash_partial(
    const short* __restrict__ hq, const short* __restrict__ Kb,
    const short* __restrict__ Vt, const int* __restrict__ mask,
    float* __restrict__ pm, float* __restrict__ pl, float* __restrict__ pO,
    int L, int NCH) {
  int ch = blockIdx.x, b = blockIdx.y;
  int C = L / NCH;
  int t = threadIdx.x, wave = t >> 6, lane = t & 63, quad = lane >> 4, l16 = lane & 15;
  __shared__ __align__(16) short Plds[4][16 * 40];  // [q][40-stride], 32 keys used
  short* myP = &Plds[wave][0];
  const short* qbase = hq + ((size_t)b * ML + l16) * DM + wave * HD;
  bf16x8 bq0 = *(const bf16x8*)(qbase + quad * 8);       // B-operand: Q[q=l16][dims]
  bf16x8 bq1 = *(const bf16x8*)(qbase + 32 + quad * 8);
  f32x4 z = {0.f, 0.f, 0.f, 0.f};
  float m_run = -1e30f, l_run = 0.f;  // state for query q = l16
  f32x4 O[4];                         // O[d][r]: q = quad*4+r, dim = d*16+l16
#pragma unroll
  for (int d = 0; d < 4; d++) O[d] = z;
  int j0 = ch * C;
  const float L2E = 1.44269504f;
  const int* mrow = mask + (size_t)b * L + j0;
  const short* k0 = Kb + ((size_t)b * L + j0 + l16) * DM + wave * HD + quad * 8;
  const short* vbase = Vt + ((size_t)b * DM + wave * HD + l16) * L + j0 + quad * 8;
  const size_t vstep = (size_t)16 * L;  // d-stride (elements)
  for (int jt = 0; jt < C; jt += 32) {
    f32x4 S[2];  // S[tt][r] = score[key = jt+tt*16+quad*4+r][q = l16]
#pragma unroll
    for (int tt = 0; tt < 2; tt++) {
      const short* kb = k0 + (size_t)(jt + tt * 16) * DM;  // A-row = key (l16 in k0)
      bf16x8 a0 = *(const bf16x8*)kb;
      bf16x8 a1 = *(const bf16x8*)(kb + 32);
      f32x4 sc = MFMA16(a0, bq0, z);
      sc = MFMA16(a1, bq1, sc);
      int4 mk = *(const int4*)(mrow + jt + tt * 16 + quad * 4);
      S[tt][0] = mk.x ? sc[0] * 0.125f : -1e30f;
      S[tt][1] = mk.y ? sc[1] * 0.125f : -1e30f;
      S[tt][2] = mk.z ? sc[2] * 0.125f : -1e30f;
      S[tt][3] = mk.w ? sc[3] * 0.125f : -1e30f;
    }
    // tile max over this lane's 8 keys, then across the 4 quads (same-q lanes)
    float v = fmaxf(fmaxf(fmaxf(S[0][0], S[0][1]), fmaxf(S[0][2], S[0][3])),
                    fmaxf(fmaxf(S[1][0], S[1][1]), fmaxf(S[1][2], S[1][3])));
    v = fmaxf(v, __shfl_xor(v, 16, 64));
    v = fmaxf(v, __shfl_xor(v, 32, 64));
    float nm = fmaxf(m_run, v);
    float alpha = exp2f((m_run - nm) * L2E);
    m_run = nm;
    float p[2][4];
    float ps = 0.f;
#pragma unroll
    for (int tt = 0; tt < 2; tt++)
#pragma unroll
      for (int r = 0; r < 4; r++) {
        p[tt][r] = exp2f((S[tt][r] - nm) * L2E);
        ps += p[tt][r];
      }
    ps += __shfl_xor(ps, 16, 64);
    ps += __shfl_xor(ps, 32, 64);
    l_run = l_run * alpha + ps;
    // broadcast alpha (q=l16, uniform across quads -> lanes 0..15 valid) to O's q-space
    float alr[4];
#pragma unroll
    for (int r = 0; r < 4; r++) alr[r] = __shfl(alpha, quad * 4 + r, 64);
#pragma unroll
    for (int d = 0; d < 4; d++)
#pragma unroll
      for (int r = 0; r < 4; r++) O[d][r] *= alr[r];
    // write P[q=l16][key]: key = tt*16 + quad*4 + r at offset == key index
#pragma unroll
    for (int tt = 0; tt < 2; tt++) {
      s16x4 pk;
#pragma unroll
      for (int r = 0; r < 4; r++) pk[r] = f2bf(p[tt][r]);
      *(s16x4*)(myP + l16 * 40 + tt * 16 + quad * 4) = pk;
    }
    __builtin_amdgcn_wave_barrier();
    __builtin_amdgcn_s_waitcnt(0xc07f);      // lgkmcnt(0): wave-local P writes done
    __builtin_amdgcn_sched_barrier(0);       // rule #18: stop hoisting past the wait
    bf16x8 ap = *(const bf16x8*)(myP + l16 * 40 + quad * 8);  // A: row=q, keys quad*8..
    const short* vb = vbase + jt;
#pragma unroll
    for (int d = 0; d < 4; d++) {
      bf16x8 bv = *(const bf16x8*)(vb + (size_t)d * vstep);
      O[d] = MFMA16(ap, bv, O[d]);
    }
  }
  size_t base = (((size_t)b * NCH + ch) * NH + wave) * ML;
  if (lane < 16) {
    pm[base + l16] = m_run;
    pl[base + l16] = l_run;
  }
#pragma unroll
  for (int d = 0; d < 4; d++)
#pragma unroll
    for (int r = 0; r < 4; r++)
      pO[(base + quad * 4 + r) * 64 + d * 16 + l16] = O[d][r];
}

// ---------------- reduce partials + Wo + gate + (next Wq | final out), per batch ----------------
__global__ __launch_bounds__(256, 2) void epilogue(
    const float* __restrict__ pm, const float* __restrict__ pl,
    const float* __restrict__ pO, int NCH,
    float* __restrict__ mem, const short* __restrict__ WoT,
    const short* __restrict__ WgT, const short* __restrict__ bg,
    const short* __restrict__ WqT, short* __restrict__ hq,
    void* __restrict__ outb, const int* __restrict__ flag) {
  int b = blockIdx.x, t = threadIdx.x;
  int isf = flag[0];
  __shared__ float w_lds[NCH_MAX * 64];
  __shared__ float invL[64];
  __shared__ __align__(16) short vec_bf[ML * DM];
  __shared__ __align__(16) short mem_bf[ML * DM];
  __shared__ __align__(16) short attn_bf[ML * DM];
  __shared__ float attn_f[ML * DM];
  __shared__ __align__(16) short memn_bf[ML * DM];

  for (int idx = t; idx < ML * DM; idx += 256)
    mem_bf[idx] = f2bf(mem[(size_t)b * ML * DM + idx]);
  if (t < 64) {  // t = n*16 + i
    size_t base = (size_t)b * NCH * NH * ML + t;
    float M = -1e30f;
    for (int ch = 0; ch < NCH; ch++)
      M = fmaxf(M, pm[base + (size_t)ch * NH * ML]);
    float Ls = 0.f;
    for (int ch = 0; ch < NCH; ch++) {
      float w = exp2f((pm[base + (size_t)ch * NH * ML] - M) * 1.44269504f);
      w_lds[ch * 64 + t] = w;
      Ls += w * pl[base + (size_t)ch * NH * ML];
    }
    invL[t] = 1.0f / Ls;
  }
  __syncthreads();
  {
    int n = t >> 6, d = t & 63;
    for (int i = 0; i < 16; i++) {
      size_t pb = ((size_t)b * NCH * NH * ML + n * ML + i) * 64 + d;
      float o = 0.f;
      for (int ch = 0; ch < NCH; ch++)
        o += w_lds[ch * 64 + n * 16 + i] * pO[pb + (size_t)ch * NH * ML * 64];
      vec_bf[i * DM + n * 64 + d] = f2bf(o * invL[n * 16 + i]);
    }
  }
  __syncthreads();
  int wave = t >> 6, lane = t & 63, quad = lane >> 4, l16 = lane & 15;
  f32x4 z = {0.f, 0.f, 0.f, 0.f};
  f32x4 acc[4];
#pragma unroll
  for (int c = 0; c < 4; c++) acc[c] = z;
#pragma unroll
  for (int kk = 0; kk < 8; kk++) {
    bf16x8 a = *(const bf16x8*)(vec_bf + l16 * DM + kk * 32 + quad * 8);
#pragma unroll
    for (int ct = 0; ct < 4; ct++) {
      const short* wb = WoT + (size_t)(wave * 64 + ct * 16 + l16) * DM + kk * 32 + quad * 8;
      acc[ct] = MFMA16(a, *(const bf16x8*)wb, acc[ct]);
    }
  }
#pragma unroll
  for (int ct = 0; ct < 4; ct++)
#pragma unroll
    for (int r = 0; r < 4; r++) {
      int row = quad * 4 + r, col = wave * 64 + ct * 16 + l16;
      attn_f[row * DM + col] = acc[ct][r];
      attn_bf[row * DM + col] = f2bf(acc[ct][r]);
    }
  __syncthreads();
  f32x4 g[4];
#pragma unroll
  for (int c = 0; c < 4; c++) g[c] = z;
#pragma unroll
  for (int kk = 0; kk < 16; kk++) {
    bf16x8 a = (kk < 8)
        ? *(const bf16x8*)(mem_bf + l16 * DM + kk * 32 + quad * 8)
        : *(const bf16x8*)(attn_bf + l16 * DM + (kk - 8) * 32 + quad * 8);
#pragma unroll
    for (int ct = 0; ct < 4; ct++) {
      const short* wb = WgT + (size_t)(wave * 64 + ct * 16 + l16) * 512 + kk * 32 + quad * 8;
      g[ct] = MFMA16(a, *(const bf16x8*)wb, g[ct]);
    }
  }
#pragma unroll
  for (int ct = 0; ct < 4; ct++)
#pragma unroll
    for (int r = 0; r < 4; r++) {
      int row = quad * 4 + r, col = wave * 64 + ct * 16 + l16;
      float x = g[ct][r] + bf2f(bg[col]);
      float gg = 1.0f / (1.0f + exp2f(-x * 1.44269504f));
      float old = mem[(size_t)b * ML * DM + row * DM + col];
      float mn = gg * old + (1.0f - gg) * attn_f[row * DM + col];
      mem[(size_t)b * ML * DM + row * DM + col] = mn;
      memn_bf[row * DM + col] = f2bf(mn);
      if (outb) {
        size_t oi = (size_t)b * ML * DM + row * DM + col;
        if (isf) ((float*)outb)[oi] = mn;
        else ((short*)outb)[oi] = f2bf(mn);
      }
    }
  __syncthreads();
  if (WqT) {
    f32x4 h[4];
#pragma unroll
    for (int c = 0; c < 4; c++) h[c] = z;
#pragma unroll
    for (int kk = 0; kk < 8; kk++) {
      bf16x8 a = *(const bf16x8*)(memn_bf + l16 * DM + kk * 32 + quad * 8);
#pragma unroll
      for (int ct = 0; ct < 4; ct++) {
        const short* wb = WqT + (size_t)(wave * 64 + ct * 16 + l16) * DM + kk * 32 + quad * 8;
        h[ct] = MFMA16(a, *(const bf16x8*)wb, h[ct]);
      }
    }
#pragma unroll
    for (int ct = 0; ct < 4; ct++)
#pragma unroll
      for (int r = 0; r < 4; r++)
        hq[(size_t)b * ML * DM + (quad * 4 + r) * DM + wave * 64 + ct * 16 + l16] = f2bf(h[ct][r]);
  }
}

// ---------------- launch ----------------
extern "C" void kernel_launch(void* const* d_in, const int* in_sizes, int n_in,
                              void* d_out, int out_size, void* d_ws, size_t ws_size,
                              hipStream_t stream) {
  const void* pattern = d_in[0];
  const void* graph = d_in[1];
  const int* pmask = (const int*)d_in[2];
  const int* gmask = (const int*)d_in[3];

  char* ws = (char*)d_ws;
  size_t off = 0;
  auto alloc = [&](size_t bytes) {
    void* p = ws + off;
    off = (off + bytes + 255) & ~(size_t)255;
    return p;
  };
  int* flag = (int*)alloc(4);
  // WT order: 0 pWqT 1 pWkT 2 pWvT 3 pWoT 4 pWgT 5 gWqT 6 gWkT 7 gWvT 8 gWoT 9 gWgT
  int rows[10] = {256, 256, 256, 256, 512, 256, 256, 256, 256, 512};
  int srcidx[10] = {4, 5, 6, 7, 8, 10, 11, 12, 13, 14};
  short* WT[10];
  for (int i = 0; i < 10; i++) WT[i] = (short*)alloc((size_t)rows[i] * 256 * 2);
  short* bgc = (short*)alloc(512 * 2);  // [p_bg(256), g_bg(256)]
  short* Kp = (short*)alloc((size_t)BB * PLEN * DM * 2);
  short* Vpt = (short*)alloc((size_t)BB * PLEN * DM * 2);
  short* Kg = (short*)alloc((size_t)BB * GLEN * DM * 2);
  short* Vgt = (short*)alloc((size_t)BB * GLEN * DM * 2);
  short* hq = (short*)alloc((size_t)BB * ML * DM * 2);
  float* memf = (float*)alloc((size_t)BB * ML * DM * 4);
  float* pm = (float*)alloc((size_t)BB * NCH_MAX * NH * ML * 4);
  float* pl = (float*)alloc((size_t)BB * NCH_MAX * NH * ML * 4);
  float* pO = (float*)alloc((size_t)BB * NCH_MAX * NH * ML * 64 * 4);  // 8.4 MB
  float* partG = (float*)alloc((size_t)(BB * GLEN / 64) * 256 * 4);    // 4.2 MB
  if (off > ws_size) return;  // ws too small: output stays zero -> diagnostic signal

  detect_dtype<<<dim3(1), dim3(256), 0, stream>>>((const short*)pattern, flag);

  WTArgs wa;
  for (int i = 0; i < 10; i++) {
    wa.src[i] = d_in[srcidx[i]];
    wa.dst[i] = WT[i];
    wa.rows[i] = rows[i];
  }
  transpose_w<<<dim3(16, 8, 10), dim3(32, 8), 0, stream>>>(wa, flag);
  conv_bias<<<dim3(1), dim3(256), 0, stream>>>(d_in[9], d_in[15], bgc, flag);

  // fused convert + mean-partials + K/V projection (graph produces partials)
  proj_kv_fused<<<dim3(BB * GLEN / 64), dim3(512), 0, stream>>>(
      graph, WT[6], WT[7], Kg, Vgt, GLEN, partG, flag);
  proj_kv_fused<<<dim3(BB * PLEN / 64), dim3(512), 0, stream>>>(
      pattern, WT[1], WT[2], Kp, Vpt, PLEN, (float*)nullptr, flag);
  finalize_q0<<<dim3(BB * ML), dim3(256), 0, stream>>>(partG, d_in[4], memf, hq, flag);

  for (int s = 0; s < 3; s++) {
    // pattern attention
    flash_partial<<<dim3(8, BB), dim3(256), 0, stream>>>(hq, Kp, Vpt, pmask, pm, pl, pO, PLEN, 8);
    epilogue<<<dim3(BB), dim3(256), 0, stream>>>(pm, pl, pO, 8, memf, WT[3], WT[4], bgc,
                                                 (const short*)WT[5], hq, (void*)nullptr, flag);
    // graph attention
    bool last = (s == 2);
    flash_partial<<<dim3(32, BB), dim3(256), 0, stream>>>(hq, Kg, Vgt, gmask, pm, pl, pO, GLEN, 32);
    epilogue<<<dim3(BB), dim3(256), 0, stream>>>(pm, pl, pO, 32, memf, WT[8], WT[9], bgc + 256,
                                                 last ? (const short*)nullptr : (const short*)WT[0],
                                                 hq, last ? d_out : (void*)nullptr, flag);
  }
}